// Round 9
// baseline (359.459 us; speedup 1.0000x reference)
//
#include <hip/hip_runtime.h>
#include <stdint.h>

#define N_NODES 50000
#define E_EDGES 800000
#define HID 128
#define NG16 50000             // E_EDGES / 16
#define BE 128                 // edges per block (fallback kernel)
#define XS_STRIDE 264
#define YS_STRIDE 136
#define HS_STRIDE 132          // 66 words ≡ 2 mod 32 -> 2-way (free) A reads

typedef unsigned short u16;
typedef unsigned char u8;
typedef __attribute__((ext_vector_type(8))) short svec8;
typedef __attribute__((ext_vector_type(16))) float fvec16;
typedef __attribute__((ext_vector_type(4))) float fvec4;
typedef __attribute__((ext_vector_type(4))) unsigned uvec4;
typedef __attribute__((ext_vector_type(2))) float fvec2;

union frag_u { unsigned u[4]; svec8 s; };
union pk8_u { u16 h[8]; svec8 s; };

__device__ __forceinline__ float bf2f(u16 u) {
    union { unsigned int i; float f; } v; v.i = ((unsigned int)u) << 16; return v.f;
}
__device__ __forceinline__ u16 f2bf(float f) {
    union { float f; unsigned int i; } v; v.f = f;
    unsigned int u = v.i;
    return (u16)((u + 0x7fffu + ((u >> 16) & 1u)) >> 16);   // RNE
}
__device__ __forceinline__ unsigned f2u(float f) {
    union { float f; unsigned i; } v; v.f = f; return v.i;
}
__device__ __forceinline__ float silu_f(float x) {
    return x * __builtin_amdgcn_rcpf(1.0f + __expf(-x));
}
__device__ __forceinline__ float ldf(const void* p, size_t i, int is_bf) {
    return is_bf ? bf2f(((const u16*)p)[i]) : ((const float*)p)[i];
}
__device__ __forceinline__ int ldi(const void* p, size_t i, int is_i64) {
    return is_i64 ? ((const int*)p)[2 * i] : ((const int*)p)[i];
}

// ---- dtype detection (fallback path only) ----
__global__ void detect_kernel(const void* __restrict__ h,
                              const void* __restrict__ eidx,
                              int* __restrict__ flags) {
    __shared__ int cnt_bf, cnt_i64;
    if (threadIdx.x == 0) { cnt_bf = 0; cnt_i64 = 0; }
    __syncthreads();
    const int t = threadIdx.x;
    unsigned u = ((const u16*)h)[2 * t];
    unsigned e = (u >> 7) & 0xFFu;
    atomicAdd(&cnt_bf, (e >= 100u && e <= 140u) ? 1 : 0);
    atomicAdd(&cnt_i64, (((const int*)eidx)[2 * t + 1] == 0) ? 1 : 0);
    __syncthreads();
    if (t == 0) { flags[0] = (cnt_bf >= 128); flags[1] = (cnt_i64 >= 128); }
}

// ---- prep: self-detect dtypes + build fragment-ordered W1f/W2f + f32 coef arrays ----
// W1f: precompute B-frags, fi=(ks*8+t)*64+lane -> coalesced 16B loads there.
// W2f: edge-kernel B-frags (permuted k), fi=(t*4+c)*64+ln.
__global__ __launch_bounds__(256) void prep_w(
    const void* __restrict__ W1, const void* __restrict__ W2,
    const void* __restrict__ b2, const void* __restrict__ W3,
    const void* __restrict__ h, const void* __restrict__ eidx,
    u16* __restrict__ W1f, u16* __restrict__ W2f,
    float* __restrict__ w1p, float* __restrict__ b2f, float* __restrict__ w3f,
    int* __restrict__ flags)
{
    __shared__ int cnt_bf, cnt_i64;
    const int tid = threadIdx.x;
    if (tid == 0) { cnt_bf = 0; cnt_i64 = 0; }
    __syncthreads();
    {
        unsigned u = ((const u16*)h)[2 * tid];
        unsigned ex = (u >> 7) & 0xFFu;
        atomicAdd(&cnt_bf, (ex >= 100u && ex <= 140u) ? 1 : 0);
        atomicAdd(&cnt_i64, (((const int*)eidx)[2 * tid + 1] == 0) ? 1 : 0);
    }
    __syncthreads();
    const int is_bf = (cnt_bf >= 128);
    const int bx = blockIdx.x;
    if (bx < 16) {
        int fi = bx * 256 + tid;                    // 0..4095
        int ks = fi >> 9, t = (fi >> 6) & 7, lane = fi & 63;
        int l31 = lane & 31, hi = lane >> 5;
        int kk = ks * 16 + hi * 8;
        int k0 = (t < 4) ? kk : 128 + kk;
        int c  = (t < 4) ? t * 32 + l31 : (t - 4) * 32 + l31;
        pk8_u tmp;
        #pragma unroll
        for (int j = 0; j < 8; ++j)
            tmp.h[j] = f2bf(ldf(W1, (size_t)(k0 + j) * 128 + c, is_bf));
        *(svec8*)(W1f + fi * 8) = tmp.s;
    } else if (bx < 24) {
        int fi = (bx - 16) * 256 + tid;             // 0..2047
        int t = fi >> 8, cc = (fi >> 6) & 3, ln = fi & 63;
        int n = t * 16 + (ln & 15), kg = ln >> 4;
        pk8_u tmp;
        #pragma unroll
        for (int j = 0; j < 8; ++j) {
            int feat = (j & 3) * 32 + cc * 8 + kg * 2 + (j >> 2);
            tmp.h[j] = f2bf(ldf(W2, (size_t)feat * 128 + n, is_bf));
        }
        *(svec8*)(W2f + fi * 8) = tmp.s;
    } else {
        if (tid < 128) {
            int cc = tid >> 5, kgs = (tid >> 3) & 3, d = (tid >> 2) & 1, e2 = tid & 3;
            int feat = e2 * 32 + cc * 8 + kgs * 2 + d;
            w1p[tid] = ldf(W1, (size_t)256 * 128 + feat, is_bf);
            b2f[tid] = ldf(b2, tid, is_bf);
            w3f[tid] = ldf(W3, tid, is_bf);
        }
        if (tid == 0) { flags[0] = is_bf; flags[1] = (cnt_i64 >= 128); }
    }
}

// ---- precompute: P fp8 permuted; lane's 32 gather bytes contiguous for edge kernel.
// Byte b of half: kg=b>>5, s=(b>>3)&3, d=(b>>2)&1, e=b&3 -> feature e*32+s*8+kg*2+d.
__global__ __launch_bounds__(256) void precompute_p(
    const void* __restrict__ h, const void* __restrict__ b1,
    const u16* __restrict__ W1f, const int* __restrict__ flags,
    u8* __restrict__ P)
{
    __shared__ __align__(16) u16 Hs[128 * HS_STRIDE];   // 33.8 KB
    const int tid = threadIdx.x;
    const int is_bf = flags[0];
    const int base = blockIdx.x * 128;
    {
        const int rr = tid >> 5, c = tid & 31;
        for (int it = 0; it < 16; ++it) {
            int row = it * 8 + rr;
            int node = base + row; if (node > N_NODES - 1) node = N_NODES - 1;
            u16* dst = &Hs[row * HS_STRIDE + c * 4];
            if (is_bf) {
                *(uint2*)dst = *(const uint2*)((const u16*)h + (size_t)node * HID + c * 4);
            } else {
                float4 v = *(const float4*)((const float*)h + (size_t)node * HID + c * 4);
                uint2 w;
                w.x = (unsigned)f2bf(v.x) | ((unsigned)f2bf(v.y) << 16);
                w.y = (unsigned)f2bf(v.z) | ((unsigned)f2bf(v.w) << 16);
                *(uint2*)dst = w;
            }
        }
    }
    __syncthreads();
    const int lane = tid & 63, wv = tid >> 6, l31 = lane & 31, hi = lane >> 5;
    float b1v[4];
    #pragma unroll
    for (int s = 0; s < 4; ++s) b1v[s] = ldf(b1, s * 32 + l31, is_bf);
    fvec16 acc[8] = {};
    for (int ks = 0; ks < 8; ++ks) {
        const int kk = ks * 16 + hi * 8;
        svec8 af = *(const svec8*)(&Hs[(wv * 32 + l31) * HS_STRIDE + kk]);
        #pragma unroll
        for (int t = 0; t < 8; ++t) {
            svec8 bf = *(const svec8*)(W1f + ((ks * 8 + t) * 64 + lane) * 8);  // coalesced
            acc[t] = __builtin_amdgcn_mfma_f32_32x32x16_bf16(af, bf, acc[t], 0, 0, 0);
        }
    }
    // l31 = s*8 + kg*2 + d  ->  dword offset kg*32 + s*8 + d*4; bytes e=0..3 = t index
    const int off = ((l31 & 7) >> 1) * 32 + (l31 >> 3) * 8 + (l31 & 1) * 4;
    #pragma unroll
    for (int r = 0; r < 16; ++r) {
        int m = (r & 3) + 8 * (r >> 2) + 4 * hi;
        int node = base + wv * 32 + m;
        if (node < N_NODES) {
            int q = __builtin_amdgcn_cvt_pk_fp8_f32(acc[0][r] + b1v[0], acc[1][r] + b1v[1], 0, false);
            q     = __builtin_amdgcn_cvt_pk_fp8_f32(acc[2][r] + b1v[2], acc[3][r] + b1v[3], q, true);
            *(unsigned*)(P + (size_t)node * 256 + off) = (unsigned)q;
            int q2 = __builtin_amdgcn_cvt_pk_fp8_f32(acc[4][r], acc[5][r], 0, false);
            q2     = __builtin_amdgcn_cvt_pk_fp8_f32(acc[6][r], acc[7][r], q2, true);
            *(unsigned*)(P + (size_t)node * 256 + 128 + off) = (unsigned)q2;
        }
    }
}

// ---- edge phi loop: no atomics, no pipeline, branch-free when specialized ----
__device__ __forceinline__ void phi_loop(
    const u8* __restrict__ P, const void* __restrict__ edge_attr,
    const void* __restrict__ edge_index, const u16* W2s,
    const float* w1s, const float* b2s, const float* w3s,
    float* __restrict__ phis, int lane, int wid, int nw, int is_bf, int is_i64)
{
    const int m = lane & 15, kg = lane >> 4;
    for (int g = wid; g < NG16; g += nw) {
        const size_t e0 = (size_t)g * 16 + m;
        const int row = is_i64 ? ((const int*)edge_index)[2 * e0]
                               : ((const int*)edge_index)[e0];
        const int col = is_i64 ? ((const int*)edge_index)[2 * ((size_t)E_EDGES + e0)]
                               : ((const int*)edge_index)[(size_t)E_EDGES + e0];
        const float ea = is_bf ? bf2f(((const u16*)edge_attr)[e0])
                               : ((const float*)edge_attr)[e0];
        const u8* pr = P + (size_t)row * 256 + kg * 32;
        const u8* pc = P + (size_t)col * 256 + 128 + kg * 32;
        uvec4 a0 = *(const uvec4*)(pr);
        uvec4 a1 = *(const uvec4*)(pr + 16);
        uvec4 c0 = *(const uvec4*)(pc);
        uvec4 c1 = *(const uvec4*)(pc + 16);
        unsigned P1[8] = {a0[0], a0[1], a0[2], a0[3], a1[0], a1[1], a1[2], a1[3]};
        unsigned P2[8] = {c0[0], c0[1], c0[2], c0[3], c1[0], c1[1], c1[2], c1[3]};
        fvec4 acc[8] = {};
        #pragma unroll
        for (int s = 0; s < 4; ++s) {
            const int k0 = s * 32 + kg * 8;
            float4 wla = *(const float4*)(&w1s[k0]);
            float4 wlb = *(const float4*)(&w1s[k0 + 4]);
            frag_u af;
            #pragma unroll
            for (int d = 0; d < 2; ++d) {
                const int u1 = (int)P1[s * 2 + d], u2 = (int)P2[s * 2 + d];
                fvec2 a01 = __builtin_amdgcn_cvt_pk_f32_fp8(u1, false);
                fvec2 a23 = __builtin_amdgcn_cvt_pk_f32_fp8(u1, true);
                fvec2 b01 = __builtin_amdgcn_cvt_pk_f32_fp8(u2, false);
                fvec2 b23 = __builtin_amdgcn_cvt_pk_f32_fp8(u2, true);
                const float* wl = d ? &wlb.x : &wla.x;
                float x0 = a01[0] + b01[0] + ea * wl[0];
                float x1 = a01[1] + b01[1] + ea * wl[1];
                float x2 = a23[0] + b23[0] + ea * wl[2];
                float x3 = a23[1] + b23[1] + ea * wl[3];
                float y0 = silu_f(x0), y1 = silu_f(x1);
                float y2 = silu_f(x2), y3 = silu_f(x3);
                af.u[d * 2 + 0] = (f2u(y0) >> 16) | (f2u(y1) & 0xFFFF0000u);
                af.u[d * 2 + 1] = (f2u(y2) >> 16) | (f2u(y3) & 0xFFFF0000u);
            }
            #pragma unroll
            for (int t = 0; t < 8; ++t) {
                svec8 bf = *(const svec8*)(&W2s[((t * 4 + s) * 64 + lane) * 8]);
                acc[t] = __builtin_amdgcn_mfma_f32_16x16x32_bf16(af.s, bf, acc[t], 0, 0, 0);
            }
        }
        float s4[4] = {0.0f, 0.0f, 0.0f, 0.0f};
        #pragma unroll
        for (int t = 0; t < 8; ++t) {
            const float bb = b2s[t * 16 + m];
            const float ww = w3s[t * 16 + m];
            #pragma unroll
            for (int r = 0; r < 4; ++r)
                s4[r] += silu_f(acc[t][r] + bb) * ww;
        }
        #pragma unroll
        for (int r = 0; r < 4; ++r) {
            s4[r] += __shfl_xor(s4[r], 1);
            s4[r] += __shfl_xor(s4[r], 2);
            s4[r] += __shfl_xor(s4[r], 4);
            s4[r] += __shfl_xor(s4[r], 8);
        }
        if (m < 4)
            phis[(size_t)g * 16 + kg * 4 + m] = s4[m];
    }
}

__global__ __launch_bounds__(256, 2) void egnn_phi(
    const u8* __restrict__ P, const void* __restrict__ edge_attr,
    const void* __restrict__ edge_index, const u16* __restrict__ W2f,
    const float* __restrict__ w1p, const float* __restrict__ b2f,
    const float* __restrict__ w3f, float* __restrict__ phis,
    const int* __restrict__ flags)
{
    __shared__ __align__(16) u16 W2s[16384];
    __shared__ float w1s[128], b2s[128], w3s[128];
    const int tid = threadIdx.x;
    #pragma unroll
    for (int i = 0; i < 8; ++i) {          // coalesced 16B copies
        int f = i * 256 + tid;
        *(svec8*)(&W2s[f * 8]) = *(const svec8*)(W2f + f * 8);
    }
    if (tid < 128) { w1s[tid] = w1p[tid]; b2s[tid] = b2f[tid]; w3s[tid] = w3f[tid]; }
    const int is_bf = flags[0], is_i64 = flags[1];
    __syncthreads();
    const int lane = tid & 63, wv = tid >> 6;
    const int wid = blockIdx.x * 4 + wv, nw = gridDim.x * 4;
    if (!is_bf && is_i64)
        phi_loop(P, edge_attr, edge_index, W2s, w1s, b2s, w3s, phis, lane, wid, nw, 0, 1);
    else
        phi_loop(P, edge_attr, edge_index, W2s, w1s, b2s, w3s, phis, lane, wid, nw, is_bf, is_i64);
}

// ---- scatter: one thread per edge; atomics hidden by massive TLP ----
__global__ __launch_bounds__(256) void scatter_kernel(
    const float* __restrict__ phis, const void* __restrict__ coord_diff,
    const void* __restrict__ edge_index, float* __restrict__ agg,
    const int* __restrict__ flags)
{
    const int e = blockIdx.x * 256 + threadIdx.x;
    if (e >= E_EDGES) return;
    const int is_bf = flags[0], is_i64 = flags[1];
    const float phi = phis[e];
    const int r = ldi(edge_index, (size_t)e, is_i64);
    const float cx = ldf(coord_diff, (size_t)e * 3 + 0, is_bf);
    const float cy = ldf(coord_diff, (size_t)e * 3 + 1, is_bf);
    const float cz = ldf(coord_diff, (size_t)e * 3 + 2, is_bf);
    atomicAdd(&agg[r * 3 + 0], cx * phi);
    atomicAdd(&agg[r * 3 + 1], cy * phi);
    atomicAdd(&agg[r * 3 + 2], cz * phi);
}

// ================= fallback (round-3, verified) when ws too small =================
__global__ void transpose_w(const void* __restrict__ W1, const void* __restrict__ W2,
                            u16* __restrict__ W1t, u16* __restrict__ W2t,
                            const int* __restrict__ flags) {
    const int is_bf = flags[0];
    int n = blockIdx.x;
    int k = threadIdx.x;
    W1t[n * 256 + k] = f2bf(ldf(W1, (size_t)k * 128 + n, is_bf));
    if (k < 128) W2t[n * 128 + k] = f2bf(ldf(W2, (size_t)k * 128 + n, is_bf));
}

__global__ __launch_bounds__(256, 2) void egnn_edge_kernel(
    const void* __restrict__ h, const void* __restrict__ coord_diff,
    const void* __restrict__ edge_attr, const void* __restrict__ edge_index,
    const void* __restrict__ W1, const void* __restrict__ b1,
    const void* __restrict__ b2, const void* __restrict__ W3,
    const u16* __restrict__ W1t, const u16* __restrict__ W2t,
    float* __restrict__ agg, const int* __restrict__ flags)
{
    __shared__ __align__(16) u16 Xs[BE * XS_STRIDE];
    __shared__ int   rows_s[BE];
    __shared__ int   cols_s[BE];
    __shared__ float ea_s[BE];
    __shared__ float b1_s[HID], b2_s[HID], w1l_s[HID], w3_s[HID];

    const int tid = threadIdx.x;
    const int e0  = blockIdx.x * BE;
    const int is_bf  = flags[0];
    const int is_i64 = flags[1];

    if (tid < BE) {
        rows_s[tid] = ldi(edge_index, (size_t)(e0 + tid), is_i64);
        cols_s[tid] = ldi(edge_index, (size_t)(E_EDGES + e0 + tid), is_i64);
        ea_s[tid]   = ldf(edge_attr, (size_t)(e0 + tid), is_bf);
    }
    if (tid < HID) {
        b1_s[tid]  = ldf(b1, tid, is_bf);
        b2_s[tid]  = ldf(b2, tid, is_bf);
        w1l_s[tid] = ldf(W1, (size_t)256 * 128 + tid, is_bf);
        w3_s[tid]  = ldf(W3, tid, is_bf);
    }
    __syncthreads();
    {
        const int gg = tid >> 4, c = tid & 15;
        #pragma unroll
        for (int it = 0; it < 16; ++it) {
            int hr = it * 16 + gg;
            int e = hr >> 1, half = hr & 1;
            int src = half ? cols_s[e] : rows_s[e];
            svec8 v;
            if (is_bf) {
                v = *(const svec8*)((const u16*)h + (size_t)src * HID + c * 8);
            } else {
                const float* hf = (const float*)h + (size_t)src * HID + c * 8;
                float4 va = *(const float4*)hf;
                float4 vb = *(const float4*)(hf + 4);
                v[0] = (short)f2bf(va.x); v[1] = (short)f2bf(va.y);
                v[2] = (short)f2bf(va.z); v[3] = (short)f2bf(va.w);
                v[4] = (short)f2bf(vb.x); v[5] = (short)f2bf(vb.y);
                v[6] = (short)f2bf(vb.z); v[7] = (short)f2bf(vb.w);
            }
            *(svec8*)(&Xs[e * XS_STRIDE + half * 128 + c * 8]) = v;
        }
    }
    __syncthreads();
    const int lane = tid & 63;
    const int wv   = tid >> 6;
    const int l31  = lane & 31, hi = lane >> 5;
    const int col  = wv * 32 + l31;

    fvec16 acc[4] = {};
    for (int ks = 0; ks < 16; ++ks) {
        const int kk = ks * 16 + hi * 8;
        svec8 bfrag = *(const svec8*)(W1t + col * 256 + kk);
        #pragma unroll
        for (int mt = 0; mt < 4; ++mt) {
            svec8 afrag = *(const svec8*)(&Xs[(mt * 32 + l31) * XS_STRIDE + kk]);
            acc[mt] = __builtin_amdgcn_mfma_f32_32x32x16_bf16(afrag, bfrag, acc[mt], 0, 0, 0);
        }
    }
    __syncthreads();
    u16* Ys = Xs;
    #pragma unroll
    for (int mt = 0; mt < 4; ++mt)
        #pragma unroll
        for (int r = 0; r < 16; ++r) {
            int row = mt * 32 + (r & 3) + 8 * (r >> 2) + 4 * hi;
            float v = acc[mt][r] + ea_s[row] * w1l_s[col] + b1_s[col];
            Ys[row * YS_STRIDE + col] = f2bf(silu_f(v));
        }
    __syncthreads();
    fvec16 acc2[4] = {};
    for (int ks = 0; ks < 8; ++ks) {
        const int kk = ks * 16 + hi * 8;
        svec8 bfrag = *(const svec8*)(W2t + col * 128 + kk);
        #pragma unroll
        for (int mt = 0; mt < 4; ++mt) {
            svec8 afrag = *(const svec8*)(&Ys[(mt * 32 + l31) * YS_STRIDE + kk]);
            acc2[mt] = __builtin_amdgcn_mfma_f32_32x32x16_bf16(afrag, bfrag, acc2[mt], 0, 0, 0);
        }
    }
    __syncthreads();
    #pragma unroll
    for (int mt = 0; mt < 4; ++mt)
        #pragma unroll
        for (int r = 0; r < 16; ++r) {
            int row = mt * 32 + (r & 3) + 8 * (r >> 2) + 4 * hi;
            float v = acc2[mt][r] + b2_s[col];
            Ys[row * YS_STRIDE + col] = f2bf(silu_f(v));
        }
    __syncthreads();
    if (tid < BE) {
        const int e = tid;
        float phi = 0.0f;
        #pragma unroll
        for (int j = 0; j < 16; ++j) {
            svec8 x = *(const svec8*)(&Ys[e * YS_STRIDE + j * 8]);
            #pragma unroll
            for (int t = 0; t < 8; ++t)
                phi += bf2f((u16)x[t]) * w3_s[j * 8 + t];
        }
        const size_t ei = (size_t)(e0 + e);
        const int r = rows_s[e];
        atomicAdd(&agg[r * 3 + 0], ldf(coord_diff, ei * 3 + 0, is_bf) * phi);
        atomicAdd(&agg[r * 3 + 1], ldf(coord_diff, ei * 3 + 1, is_bf) * phi);
        atomicAdd(&agg[r * 3 + 2], ldf(coord_diff, ei * 3 + 2, is_bf) * phi);
    }
}

// ---- finalize: out = coord + agg/100, written in the input float dtype ----
__global__ void finalize_kernel(const void* __restrict__ coord,
                                const float* __restrict__ agg,
                                void* __restrict__ out,
                                const int* __restrict__ flags) {
    const int is_bf = flags[0];
    int i = blockIdx.x * blockDim.x + threadIdx.x;
    if (i < N_NODES * 3) {
        float v = ldf(coord, i, is_bf) + agg[i] * 0.01f;
        if (is_bf) ((u16*)out)[i] = f2bf(v);
        else       ((float*)out)[i] = v;
    }
}

extern "C" void kernel_launch(void* const* d_in, const int* in_sizes, int n_in,
                              void* d_out, int out_size, void* d_ws, size_t ws_size,
                              hipStream_t stream) {
    const void* h          = d_in[0];
    const void* coord      = d_in[1];
    const void* coord_diff = d_in[2];
    // d_in[3] = coord_cross (unused)
    const void* edge_attr  = d_in[4];
    const void* edge_index = d_in[5];
    const void* W1 = d_in[6];
    const void* b1 = d_in[7];
    const void* W2 = d_in[8];
    const void* b2 = d_in[9];
    const void* W3 = d_in[10];

    char* ws    = (char*)d_ws;
    float* agg  = (float*)ws;                        // 600,000 B
    u16* W1f    = (u16*)(ws + 600064);               // 65,536 B (fallback: W1t)
    u16* W2f    = (u16*)(ws + 665600);               // 32,768 B (fallback: W2t)
    float* w1p  = (float*)(ws + 698368);             // 512 B
    float* b2f  = (float*)(ws + 698880);             // 512 B
    float* w3f  = (float*)(ws + 699392);             // 512 B
    int* flags  = (int*)(ws + 699904);               // 64 B
    float* phis = (float*)(ws + 700416);             // 3,200,000 B
    u8* P       = (u8*)(ws + 3900416);               // 12,800,000 B
    const size_t NEED = 3900416 + (size_t)N_NODES * 256;   // ~16.7 MB (r4 proved ws >= 26 MB)

    hipMemsetAsync(agg, 0, N_NODES * 3 * sizeof(float), stream);
    if (ws_size >= NEED) {
        prep_w<<<dim3(25), dim3(256), 0, stream>>>(
            W1, W2, b2, W3, h, edge_index, W1f, W2f, w1p, b2f, w3f, flags);
        precompute_p<<<dim3((N_NODES + 127) / 128), dim3(256), 0, stream>>>(
            h, b1, W1f, flags, P);
        egnn_phi<<<dim3(2048), dim3(256), 0, stream>>>(
            P, edge_attr, edge_index, W2f, w1p, b2f, w3f, phis, flags);
        scatter_kernel<<<dim3((E_EDGES + 255) / 256), dim3(256), 0, stream>>>(
            phis, coord_diff, edge_index, agg, flags);
    } else {
        detect_kernel<<<dim3(1), dim3(256), 0, stream>>>(h, edge_index, flags);
        transpose_w<<<dim3(128), dim3(256), 0, stream>>>(W1, W2, W1f, W2f, flags);
        egnn_edge_kernel<<<dim3(E_EDGES / BE), dim3(256), 0, stream>>>(
            h, coord_diff, edge_attr, edge_index, W1, b1, b2, W3, W1f, W2f, agg, flags);
    }
    finalize_kernel<<<dim3((N_NODES * 3 + 255) / 256), dim3(256), 0, stream>>>(coord, agg, d_out, flags);
}